// Round 1
// baseline (563.561 us; speedup 1.0000x reference)
//
#include <hip/hip_runtime.h>
#include <hip/hip_bf16.h>

typedef __attribute__((ext_vector_type(8))) _Float16 half8;
typedef __attribute__((ext_vector_type(4))) _Float16 half4;
typedef __attribute__((ext_vector_type(4))) float f32x4;

#define B_ 32
#define N_ 1024
#define DIN_ 512
#define H_ 8
#define DH_ 64

__device__ __forceinline__ float tanh_fast(float x) {
    float cx = fminf(fmaxf(x, -15.f), 15.f);
    float e = __expf(2.f * cx);
    return 1.f - __fdividef(2.f, e + 1.f);
}

// ---------------- kernel 1: pack adjacency into bitmask -------------------
// A: [B,N,N] f32 of {0,1}  ->  Abits: [B*N][16] u64 (bit m&63 of word m>>6)
__global__ __launch_bounds__(256) void pack_mask(const float* __restrict__ A,
                                                 unsigned long long* __restrict__ Abits) {
    int tid = blockIdx.x * 256 + threadIdx.x;
    int wave = tid >> 6;
    int lane = threadIdx.x & 63;
    float a = A[(size_t)wave * 64 + lane];
    unsigned long long m = __ballot(a != 0.f);
    if (lane == 0) Abits[wave] = m;
}

// ---------------- kernel 2: prep weights (transpose + f16 cast) -----------
// WT: [H][DH][DIN] f16  (WT[h][n][k] = Wp[h][k][n]);  Cb: [H][DH][DH] f16
__global__ __launch_bounds__(256) void prep_w(const float* __restrict__ Wp,
                                              const float* __restrict__ C,
                                              _Float16* __restrict__ WT,
                                              _Float16* __restrict__ Cb) {
    int gid = blockIdx.x * 256 + threadIdx.x;
    if (gid < H_ * DH_ * DIN_) {
        int h = gid >> 15;           // DH_*DIN_ = 32768
        int n = (gid >> 9) & 63;
        int k = gid & 511;
        WT[gid] = (_Float16)Wp[((size_t)(h * DIN_ + k)) * DH_ + n];
    } else {
        int cid = gid - H_ * DH_ * DIN_;
        if (cid < H_ * DH_ * DH_) Cb[cid] = (_Float16)C[cid];
    }
}

// ---------------- kernel 3: projection + bilinear -------------------------
// per block: (b,h,n0) 64-row tile.  Xp = X@Wp + bp ; Xc = Xp@C^T ; XpT = Xp^T
__global__ __launch_bounds__(256) void proj_kernel(const float* __restrict__ X,
                                                   const float* __restrict__ bp,
                                                   const _Float16* __restrict__ WT,
                                                   const _Float16* __restrict__ Cb,
                                                   _Float16* __restrict__ Xp,
                                                   _Float16* __restrict__ Xc,
                                                   _Float16* __restrict__ XpT) {
    __shared__ _Float16 Xb[64][136];   // X chunk (f16), pad 8 to break bank conflicts
    __shared__ _Float16 Wt[64][136];   // W^T chunk [n][k]
    __shared__ _Float16 Xs[64][72];    // Xp tile for bilinear + transpose

    int tid = threadIdx.x;
    int lane = tid & 63, w = tid >> 6;
    int blk = blockIdx.x;
    int bh = blk >> 4;                 // b*8+h
    int h = bh & 7;
    int b = bh >> 3;
    int n0 = (blk & 15) * 64;

    int r = tid >> 2, q = tid & 3;
    f32x4 acc[4] = {{0,0,0,0},{0,0,0,0},{0,0,0,0},{0,0,0,0}};

    for (int kc = 0; kc < 4; ++kc) {
        // stage X rows (f32 -> f16)
        const float4* xs = (const float4*)(X + ((size_t)b * N_ + n0 + r) * DIN_ + kc * 128 + q * 32);
#pragma unroll
        for (int i = 0; i < 8; ++i) {
            float4 v = xs[i];
            half4 hv = {(_Float16)v.x, (_Float16)v.y, (_Float16)v.z, (_Float16)v.w};
            *(half4*)&Xb[r][q * 32 + i * 4] = hv;
        }
        // stage W^T rows (already f16 + transposed)
        const half8* wsrc = (const half8*)(WT + ((size_t)h * DH_ + r) * DIN_ + kc * 128 + q * 32);
#pragma unroll
        for (int i = 0; i < 4; ++i) {
            *(half8*)&Wt[r][q * 32 + i * 8] = wsrc[i];
        }
        __syncthreads();
#pragma unroll
        for (int ks = 0; ks < 4; ++ks) {
            half8 a = *(const half8*)&Xb[w * 16 + (lane & 15)][ks * 32 + (lane >> 4) * 8];
#pragma unroll
            for (int f = 0; f < 4; ++f) {
                half8 bb = *(const half8*)&Wt[f * 16 + (lane & 15)][ks * 32 + (lane >> 4) * 8];
                acc[f] = __builtin_amdgcn_mfma_f32_16x16x32_f16(a, bb, acc[f], 0, 0, 0);
            }
        }
        __syncthreads();
    }

    // epilogue: bias, write Xp (global) and Xs (LDS)
    int rb = w * 16 + ((lane >> 4) << 2);
#pragma unroll
    for (int f = 0; f < 4; ++f) {
        int col = f * 16 + (lane & 15);
        float bias = bp[h * DH_ + col];
#pragma unroll
        for (int j = 0; j < 4; ++j) {
            _Float16 v = (_Float16)(acc[f][j] + bias);
            Xp[((size_t)bh * N_ + n0 + rb + j) * DH_ + col] = v;
            Xs[rb + j][col] = v;
        }
    }
    __syncthreads();

    // bilinear: Xc = Xs @ C^T   (B-frag reads C rows contiguously)
    f32x4 accc[4] = {{0,0,0,0},{0,0,0,0},{0,0,0,0},{0,0,0,0}};
#pragma unroll
    for (int ks = 0; ks < 2; ++ks) {
        half8 a = *(const half8*)&Xs[w * 16 + (lane & 15)][ks * 32 + (lane >> 4) * 8];
#pragma unroll
        for (int f = 0; f < 4; ++f) {
            half8 bb = *(const half8*)(Cb + ((size_t)h * DH_ + f * 16 + (lane & 15)) * DH_ + ks * 32 + (lane >> 4) * 8);
            accc[f] = __builtin_amdgcn_mfma_f32_16x16x32_f16(a, bb, accc[f], 0, 0, 0);
        }
    }
#pragma unroll
    for (int f = 0; f < 4; ++f) {
        int col = f * 16 + (lane & 15);
#pragma unroll
        for (int j = 0; j < 4; ++j) {
            Xc[((size_t)bh * N_ + n0 + rb + j) * DH_ + col] = (_Float16)accc[f][j];
        }
    }

    // XpT write via LDS bounce: XpT[bh][d][n0+ln] = Xs[ln][d]
    {
        int d = tid >> 2, qq = tid & 3;
        __align__(16) _Float16 tmp[16];
#pragma unroll
        for (int i = 0; i < 16; ++i) tmp[i] = Xs[qq * 16 + i][d];
        _Float16* dst = XpT + ((size_t)bh * DH_ + d) * N_ + n0 + qq * 16;
        *(half8*)dst = *(half8*)tmp;
        *(half8*)(dst + 8) = *(half8*)(tmp + 8);
    }
}

// ---------------- kernel 4: fused masked-tanh attention -------------------
// per block: (b,h,q0).  S = Xc@Xp^T ; P = A ? tanh(S) : 0 ; O += P@Xp ; relu
__global__ __launch_bounds__(256) void attn_kernel(const _Float16* __restrict__ Xp,
                                                   const _Float16* __restrict__ Xc,
                                                   const _Float16* __restrict__ XpT,
                                                   const unsigned long long* __restrict__ Abits,
                                                   float* __restrict__ out) {
    __shared__ _Float16 Kb[64][72];
    __shared__ _Float16 Vt[64][72];
    __shared__ _Float16 Ps[64][72];

    int tid = threadIdx.x;
    int lane = tid & 63, w = tid >> 6;
    int blk = blockIdx.x;
    int bh = blk >> 4;
    int q0 = (blk & 15) * 64;
    int b = bh >> 3, h = bh & 7;

    // Q fragments in registers (rows w*16.., k-contiguous)
    const _Float16* qbase = Xc + ((size_t)bh * N_ + q0 + w * 16 + (lane & 15)) * DH_ + (lane >> 4) * 8;
    half8 qa0 = *(const half8*)qbase;
    half8 qa1 = *(const half8*)(qbase + 32);

    f32x4 oacc[4] = {{0,0,0,0},{0,0,0,0},{0,0,0,0},{0,0,0,0}};
    int r = tid >> 2, q = tid & 3;
    int rb = w * 16 + ((lane >> 4) << 2);

    for (int mt = 0; mt < 16; ++mt) {
        __syncthreads();   // protect Kb/Vt from previous iteration's PV
        // stage K rows (linear from Xp) and V^T rows (linear from XpT)
        const half8* ksrc = (const half8*)(Xp + ((size_t)bh * N_ + mt * 64 + r) * DH_ + q * 16);
        half8 k0 = ksrc[0], k1 = ksrc[1];
        const half8* vsrc = (const half8*)(XpT + ((size_t)bh * DH_ + r) * N_ + mt * 64 + q * 16);
        half8 v0 = vsrc[0], v1 = vsrc[1];
        *(half8*)&Kb[r][q * 16] = k0;
        *(half8*)&Kb[r][q * 16 + 8] = k1;
        *(half8*)&Vt[r][q * 16] = v0;
        *(half8*)&Vt[r][q * 16 + 8] = v1;
        __syncthreads();

        // S = Q @ K^T (per wave: 16 rows x 64 cols)
        f32x4 s[4] = {{0,0,0,0},{0,0,0,0},{0,0,0,0},{0,0,0,0}};
#pragma unroll
        for (int f = 0; f < 4; ++f) {
            half8 kb0 = *(const half8*)&Kb[f * 16 + (lane & 15)][(lane >> 4) * 8];
            s[f] = __builtin_amdgcn_mfma_f32_16x16x32_f16(qa0, kb0, s[f], 0, 0, 0);
            half8 kb1 = *(const half8*)&Kb[f * 16 + (lane & 15)][32 + (lane >> 4) * 8];
            s[f] = __builtin_amdgcn_mfma_f32_16x16x32_f16(qa1, kb1, s[f], 0, 0, 0);
        }

        // mask + tanh -> P (f16 in LDS)
        unsigned long long mw[4];
#pragma unroll
        for (int j = 0; j < 4; ++j)
            mw[j] = Abits[((size_t)b * N_ + q0 + rb + j) * 16 + mt];
#pragma unroll
        for (int f = 0; f < 4; ++f) {
            int c = f * 16 + (lane & 15);
#pragma unroll
            for (int j = 0; j < 4; ++j) {
                float p = ((mw[j] >> c) & 1ULL) ? tanh_fast(s[f][j]) : 0.f;
                Ps[rb + j][c] = (_Float16)p;
            }
        }
        __syncthreads();

        // O += P @ V
#pragma unroll
        for (int ks = 0; ks < 2; ++ks) {
            half8 pa = *(const half8*)&Ps[w * 16 + (lane & 15)][ks * 32 + (lane >> 4) * 8];
#pragma unroll
            for (int f = 0; f < 4; ++f) {
                half8 vb = *(const half8*)&Vt[f * 16 + (lane & 15)][ks * 32 + (lane >> 4) * 8];
                oacc[f] = __builtin_amdgcn_mfma_f32_16x16x32_f16(pa, vb, oacc[f], 0, 0, 0);
            }
        }
    }

    // epilogue: relu, write f32 out[b][n][h*64+c]
#pragma unroll
    for (int f = 0; f < 4; ++f) {
        int col = h * DH_ + f * 16 + (lane & 15);
#pragma unroll
        for (int j = 0; j < 4; ++j) {
            out[((size_t)b * N_ + q0 + rb + j) * 512 + col] = fmaxf(oacc[f][j], 0.f);
        }
    }
}

extern "C" void kernel_launch(void* const* d_in, const int* in_sizes, int n_in,
                              void* d_out, int out_size, void* d_ws, size_t ws_size,
                              hipStream_t stream) {
    const float* X  = (const float*)d_in[0];
    const float* A  = (const float*)d_in[1];
    const float* Wp = (const float*)d_in[2];
    const float* bp = (const float*)d_in[3];
    const float* C  = (const float*)d_in[4];
    float* out = (float*)d_out;

    char* ws = (char*)d_ws;
    unsigned long long* Abits = (unsigned long long*)ws;               // 4 MB
    _Float16* WT  = (_Float16*)(ws + 4u * 1024 * 1024);                // 512 KB
    _Float16* Cb  = (_Float16*)(ws + 4u * 1024 * 1024 + 512 * 1024);   // 64 KB
    _Float16* Xp  = (_Float16*)(ws + 5u * 1024 * 1024);                // 32 MB
    _Float16* Xc  = (_Float16*)(ws + 37u * 1024 * 1024);               // 32 MB
    _Float16* XpT = (_Float16*)(ws + 69u * 1024 * 1024);               // 32 MB  (end: 101 MB)

    pack_mask<<<(B_ * N_ * N_) / (64 * 4), 256, 0, stream>>>(A, Abits);
    prep_w<<<(H_ * DH_ * DIN_ + H_ * DH_ * DH_ + 255) / 256, 256, 0, stream>>>(Wp, C, WT, Cb);
    proj_kernel<<<B_ * H_ * 16, 256, 0, stream>>>(X, bp, WT, Cb, Xp, Xc, XpT);
    attn_kernel<<<B_ * H_ * 16, 256, 0, stream>>>(Xp, Xc, XpT, Abits, out);
}

// Round 5
// 493.016 us; speedup vs baseline: 1.1431x; 1.1431x over previous
//
#include <hip/hip_runtime.h>
#include <hip/hip_bf16.h>

typedef __attribute__((ext_vector_type(8))) _Float16 half8;
typedef __attribute__((ext_vector_type(4))) _Float16 half4;
typedef __attribute__((ext_vector_type(4))) float f32x4;

#define B_ 32
#define N_ 1024
#define DIN_ 512
#define H_ 8
#define DH_ 64

// tanh(x) = 1 - 2/(exp(2x)+1); inf/denorm behavior gives exact +-1 saturation,
// tanh(0) == 0 exactly. 3 VALU + 2 trans, no clamp needed.
__device__ __forceinline__ float tanh_e(float x) {
    float e = __builtin_amdgcn_exp2f(x * 2.885390081777927f);  // exp(2x)
    float r = __builtin_amdgcn_rcpf(e + 1.f);
    return fmaf(-2.f, r, 1.f);
}

// ---------------- kernel 1: pack adjacency into bitmask -------------------
// A: [B,N,N] f32 of {0,1}  ->  Abits: [B*N][16] u64 (bit m&63 of word m>>6)
__global__ __launch_bounds__(256) void pack_mask(const float* __restrict__ A,
                                                 unsigned long long* __restrict__ Abits) {
    int tid = blockIdx.x * 256 + threadIdx.x;
    int wave = tid >> 6;
    int lane = threadIdx.x & 63;
    float a = A[(size_t)wave * 64 + lane];
    unsigned long long m = __ballot(a != 0.f);
    if (lane == 0) Abits[wave] = m;
}

// ---------------- kernel 2: prep weights (transpose + f16 cast) -----------
// WT: [H*DH][DIN] f16  (WT[h*64+n][k] = Wp[h][k][n]);  Cb: [H][DH][DH] f16
__global__ __launch_bounds__(256) void prep_w(const float* __restrict__ Wp,
                                              const float* __restrict__ C,
                                              _Float16* __restrict__ WT,
                                              _Float16* __restrict__ Cb) {
    int gid = blockIdx.x * 256 + threadIdx.x;
    if (gid < H_ * DH_ * DIN_) {
        int h = gid >> 15;           // DH_*DIN_ = 32768
        int n = (gid >> 9) & 63;
        int k = gid & 511;
        WT[gid] = (_Float16)Wp[((size_t)(h * DIN_ + k)) * DH_ + n];
    } else {
        int cid = gid - H_ * DH_ * DIN_;
        if (cid < H_ * DH_ * DH_) Cb[cid] = (_Float16)C[cid];
    }
}

// ---------------- kernel 3: projection GEMM (all 4 heads per block) -------
// block = (b, n0, half): 64 rows x 256 cols (4 heads, 1 head per wave).
// X tile staged once in LDS (f16), W fragments read from L2-resident WT.
__global__ __launch_bounds__(256) void proj_gemm(const float* __restrict__ X,
                                                 const float* __restrict__ bp,
                                                 const _Float16* __restrict__ WT,
                                                 _Float16* __restrict__ Xp) {
    __shared__ _Float16 Xb[64][72];

    int tid = threadIdx.x;
    int lane = tid & 63, w = tid >> 6;
    int blk = blockIdx.x;
    int b = blk >> 5;
    int n0 = ((blk >> 1) & 15) * 64;
    int h = (blk & 1) * 4 + w;       // head handled by this wave

    int r = tid >> 2, q = tid & 3;
    const float* xrow = X + ((size_t)b * N_ + n0 + r) * DIN_ + q * 16;

    f32x4 acc[4][4] = {};

    for (int kc = 0; kc < 8; ++kc) {
        // stage X[64][64] chunk -> f16
        float4 v0 = *(const float4*)(xrow + kc * 64 + 0);
        float4 v1 = *(const float4*)(xrow + kc * 64 + 4);
        float4 v2 = *(const float4*)(xrow + kc * 64 + 8);
        float4 v3 = *(const float4*)(xrow + kc * 64 + 12);
        half8 h0 = {(_Float16)v0.x, (_Float16)v0.y, (_Float16)v0.z, (_Float16)v0.w,
                    (_Float16)v1.x, (_Float16)v1.y, (_Float16)v1.z, (_Float16)v1.w};
        half8 h1 = {(_Float16)v2.x, (_Float16)v2.y, (_Float16)v2.z, (_Float16)v2.w,
                    (_Float16)v3.x, (_Float16)v3.y, (_Float16)v3.z, (_Float16)v3.w};
        *(half8*)&Xb[r][q * 16] = h0;
        *(half8*)&Xb[r][q * 16 + 8] = h1;
        __syncthreads();

#pragma unroll
        for (int ks = 0; ks < 2; ++ks) {
            half8 a[4];
#pragma unroll
            for (int m = 0; m < 4; ++m)
                a[m] = *(const half8*)&Xb[m * 16 + (lane & 15)][ks * 32 + (lane >> 4) * 8];
#pragma unroll
            for (int f = 0; f < 4; ++f) {
                half8 bb = *(const half8*)(WT + ((size_t)(h * 64 + f * 16 + (lane & 15))) * DIN_
                                           + kc * 64 + ks * 32 + (lane >> 4) * 8);
#pragma unroll
                for (int m = 0; m < 4; ++m)
                    acc[m][f] = __builtin_amdgcn_mfma_f32_16x16x32_f16(a[m], bb, acc[m][f], 0, 0, 0);
            }
        }
        __syncthreads();
    }

    // epilogue: bias + f16 write (coalesced 32B segments per 16-lane group)
    size_t bh = (size_t)(b * 8 + h);
#pragma unroll
    for (int f = 0; f < 4; ++f) {
        int col = f * 16 + (lane & 15);
        float bias = bp[h * 64 + col];
#pragma unroll
        for (int m = 0; m < 4; ++m) {
            int row = m * 16 + ((lane >> 4) << 2);
#pragma unroll
            for (int j = 0; j < 4; ++j) {
                Xp[(bh * N_ + n0 + row + j) * DH_ + col] = (_Float16)(acc[m][f][j] + bias);
            }
        }
    }
}

// ---------------- kernel 3b: bilinear + transpose -------------------------
// per block (bh, n0): Xc = Xp_tile @ C^T ; XpT[bh][d][n] = Xp[bh][n][d]
__global__ __launch_bounds__(256) void bil_kernel(const _Float16* __restrict__ Xp,
                                                  const _Float16* __restrict__ Cb,
                                                  _Float16* __restrict__ Xc,
                                                  _Float16* __restrict__ XpT) {
    __shared__ _Float16 Xs[64][72];

    int tid = threadIdx.x;
    int lane = tid & 63, w = tid >> 6;
    int blk = blockIdx.x;
    int bh = blk >> 4;
    int n0 = (blk & 15) * 64;
    int h = bh & 7;

    int r = tid >> 2, q = tid & 3;
    const half8* src = (const half8*)(Xp + ((size_t)bh * N_ + n0 + r) * DH_ + q * 16);
    *(half8*)&Xs[r][q * 16] = src[0];
    *(half8*)&Xs[r][q * 16 + 8] = src[1];
    __syncthreads();

    // bilinear: rows w*16..w*16+15
    f32x4 acc[4] = {{0,0,0,0},{0,0,0,0},{0,0,0,0},{0,0,0,0}};
#pragma unroll
    for (int ks = 0; ks < 2; ++ks) {
        half8 a = *(const half8*)&Xs[w * 16 + (lane & 15)][ks * 32 + (lane >> 4) * 8];
#pragma unroll
        for (int f = 0; f < 4; ++f) {
            half8 bb = *(const half8*)(Cb + ((size_t)(h * DH_ + f * 16 + (lane & 15))) * DH_
                                       + ks * 32 + (lane >> 4) * 8);
            acc[f] = __builtin_amdgcn_mfma_f32_16x16x32_f16(a, bb, acc[f], 0, 0, 0);
        }
    }
    int rb = w * 16 + ((lane >> 4) << 2);
#pragma unroll
    for (int f = 0; f < 4; ++f) {
        int col = f * 16 + (lane & 15);
#pragma unroll
        for (int j = 0; j < 4; ++j)
            Xc[((size_t)bh * N_ + n0 + rb + j) * DH_ + col] = (_Float16)acc[f][j];
    }

    // transpose: lane-permuted d => row-uniform LDS reads (conflict-free)
    {
        int d = (lane & 3) * 16 + (lane >> 2);
        __align__(16) _Float16 tmp[16];
#pragma unroll
        for (int i = 0; i < 16; ++i) tmp[i] = Xs[w * 16 + i][d];
        _Float16* dst = XpT + ((size_t)bh * DH_ + d) * N_ + n0 + w * 16;
        *(half8*)dst = *(half8*)tmp;
        *(half8*)(dst + 8) = *(half8*)(tmp + 8);
    }
}

// ---------------- kernel 4: fused masked-tanh attention -------------------
// per block: (b,h,q0).  S = Xc@Xp^T ; P = A ? tanh(S) : 0 ; O += P@Xp ; relu
__global__ __launch_bounds__(256) void attn_kernel(const _Float16* __restrict__ Xp,
                                                   const _Float16* __restrict__ Xc,
                                                   const _Float16* __restrict__ XpT,
                                                   const unsigned long long* __restrict__ Abits,
                                                   float* __restrict__ out) {
    __shared__ _Float16 Kb[64][72];
    __shared__ _Float16 Vt[64][72];
    __shared__ _Float16 Ps[64][76];   // stride 76: breaks 4-way write conflict

    int tid = threadIdx.x;
    int lane = tid & 63, w = tid >> 6;
    int blk = blockIdx.x;
    int bh = blk >> 4;
    int q0 = (blk & 15) * 64;
    int b = bh >> 3, h = bh & 7;

    // Q fragments in registers (rows w*16.., k-contiguous)
    const _Float16* qbase = Xc + ((size_t)bh * N_ + q0 + w * 16 + (lane & 15)) * DH_ + (lane >> 4) * 8;
    half8 qa0 = *(const half8*)qbase;
    half8 qa1 = *(const half8*)(qbase + 32);

    f32x4 oacc[4] = {{0,0,0,0},{0,0,0,0},{0,0,0,0},{0,0,0,0}};
    int r = tid >> 2, q = tid & 3;
    int rb = w * 16 + ((lane >> 4) << 2);
    int c16 = lane & 15;

    for (int mt = 0; mt < 16; ++mt) {
        __syncthreads();   // protect Kb/Vt from previous iteration's PV
        // stage K rows (linear from Xp) and V^T rows (linear from XpT)
        const half8* ksrc = (const half8*)(Xp + ((size_t)bh * N_ + mt * 64 + r) * DH_ + q * 16);
        half8 k0 = ksrc[0], k1 = ksrc[1];
        const half8* vsrc = (const half8*)(XpT + ((size_t)bh * DH_ + r) * N_ + mt * 64 + q * 16);
        half8 v0 = vsrc[0], v1 = vsrc[1];
        *(half8*)&Kb[r][q * 16] = k0;
        *(half8*)&Kb[r][q * 16 + 8] = k1;
        *(half8*)&Vt[r][q * 16] = v0;
        *(half8*)&Vt[r][q * 16 + 8] = v1;
        __syncthreads();

        // S = Q @ K^T (per wave: 16 rows x 64 cols)
        f32x4 s[4] = {{0,0,0,0},{0,0,0,0},{0,0,0,0},{0,0,0,0}};
#pragma unroll
        for (int f = 0; f < 4; ++f) {
            half8 kb0 = *(const half8*)&Kb[f * 16 + c16][(lane >> 4) * 8];
            s[f] = __builtin_amdgcn_mfma_f32_16x16x32_f16(qa0, kb0, s[f], 0, 0, 0);
            half8 kb1 = *(const half8*)&Kb[f * 16 + c16][32 + (lane >> 4) * 8];
            s[f] = __builtin_amdgcn_mfma_f32_16x16x32_f16(qa1, kb1, s[f], 0, 0, 0);
        }

        // mask + tanh -> P (f16 in LDS). One 64-bit shift per row, then
        // constant-position bit extracts (bits 0/16 of lo/hi words).
#pragma unroll
        for (int j = 0; j < 4; ++j) {
            unsigned long long m0 = Abits[((size_t)b * N_ + q0 + rb + j) * 16 + mt] >> c16;
            unsigned lo = (unsigned)m0, hi = (unsigned)(m0 >> 32);
            unsigned bit0 = lo & 1u, bit1 = (lo >> 16) & 1u;
            unsigned bit2 = hi & 1u, bit3 = (hi >> 16) & 1u;
            float t0 = tanh_e(s[0][j]);
            float t1 = tanh_e(s[1][j]);
            float t2 = tanh_e(s[2][j]);
            float t3 = tanh_e(s[3][j]);
            Ps[rb + j][c16]      = (_Float16)(bit0 ? t0 : 0.f);
            Ps[rb + j][16 + c16] = (_Float16)(bit1 ? t1 : 0.f);
            Ps[rb + j][32 + c16] = (_Float16)(bit2 ? t2 : 0.f);
            Ps[rb + j][48 + c16] = (_Float16)(bit3 ? t3 : 0.f);
        }
        __syncthreads();

        // O += P @ V
#pragma unroll
        for (int ks = 0; ks < 2; ++ks) {
            half8 pa = *(const half8*)&Ps[w * 16 + c16][ks * 32 + (lane >> 4) * 8];
#pragma unroll
            for (int f = 0; f < 4; ++f) {
                half8 vb = *(const half8*)&Vt[f * 16 + c16][ks * 32 + (lane >> 4) * 8];
                oacc[f] = __builtin_amdgcn_mfma_f32_16x16x32_f16(pa, vb, oacc[f], 0, 0, 0);
            }
        }
    }

    // epilogue: relu, write f32 out[b][n][h*64+c]
#pragma unroll
    for (int f = 0; f < 4; ++f) {
        int col = h * DH_ + f * 16 + c16;
#pragma unroll
        for (int j = 0; j < 4; ++j) {
            out[((size_t)b * N_ + q0 + rb + j) * 512 + col] = fmaxf(oacc[f][j], 0.f);
        }
    }
}

extern "C" void kernel_launch(void* const* d_in, const int* in_sizes, int n_in,
                              void* d_out, int out_size, void* d_ws, size_t ws_size,
                              hipStream_t stream) {
    const float* X  = (const float*)d_in[0];
    const float* A  = (const float*)d_in[1];
    const float* Wp = (const float*)d_in[2];
    const float* bp = (const float*)d_in[3];
    const float* C  = (const float*)d_in[4];
    float* out = (float*)d_out;

    char* ws = (char*)d_ws;
    unsigned long long* Abits = (unsigned long long*)ws;               // 4 MB
    _Float16* WT  = (_Float16*)(ws + 4u * 1024 * 1024);                // 512 KB
    _Float16* Cb  = (_Float16*)(ws + 4u * 1024 * 1024 + 512 * 1024);   // 64 KB
    _Float16* Xp  = (_Float16*)(ws + 5u * 1024 * 1024);                // 32 MB
    _Float16* Xc  = (_Float16*)(ws + 37u * 1024 * 1024);               // 32 MB
    _Float16* XpT = (_Float16*)(ws + 69u * 1024 * 1024);               // 32 MB  (end: 101 MB)

    pack_mask<<<(B_ * N_ * N_) / (64 * 4), 256, 0, stream>>>(A, Abits);
    prep_w<<<(H_ * DH_ * DIN_ + H_ * DH_ * DH_ + 255) / 256, 256, 0, stream>>>(Wp, C, WT, Cb);
    proj_gemm<<<B_ * 16 * 2, 256, 0, stream>>>(X, bp, WT, Xp);
    bil_kernel<<<B_ * H_ * 16, 256, 0, stream>>>(Xp, Cb, Xc, XpT);
    attn_kernel<<<B_ * H_ * 16, 256, 0, stream>>>(Xp, Xc, XpT, Abits, out);
}